// Round 1
// baseline (140.842 us; speedup 1.0000x reference)
//
#include <hip/hip_runtime.h>

// Problem constants: B=8, C=128, H=W=256, P=2, R=2, WP=3, HID=8.
// Output xp: (B, C, 260, 260) fp32. Interior = copy of x; 2-wide frame from 4
// small MLPs applied in a 4-stage sequential schedule:
//   {top0,bot0} -> {left0,right0} -> {top1,bot1} -> {left1,right1}
// Each (b,c) slice is independent -> one workgroup per slice, borders in LDS.

// map xp row/col index in {0,1,2,3,255,256,257,258,259} -> 0..8
__device__ __forceinline__ int bmap(int r) { return r < 4 ? r : r - 251; }

__device__ __forceinline__ float mlp6(const float* __restrict__ v,
                                      const float* __restrict__ W1s,  // [8][6]
                                      const float* __restrict__ B1s,  // [8]
                                      const float* __restrict__ W2s,  // [8][8]
                                      const float* __restrict__ B2s,  // [8]
                                      const float* __restrict__ W3s,  // [8]
                                      float b3s)
{
    float h1[8];
#pragma unroll
    for (int h = 0; h < 8; ++h) {
        float a = B1s[h];
#pragma unroll
        for (int q = 0; q < 6; ++q) a = fmaf(v[q], W1s[h * 6 + q], a);
        h1[h] = fmaxf(a, 0.f);
    }
    float h2[8];
#pragma unroll
    for (int g = 0; g < 8; ++g) {
        float a = B2s[g];
#pragma unroll
        for (int h = 0; h < 8; ++h) a = fmaf(h1[h], W2s[g * 8 + h], a);
        h2[g] = fmaxf(a, 0.f);
    }
    float o = b3s;
#pragma unroll
    for (int g = 0; g < 8; ++g) o = fmaf(h2[g], W3s[g], o);
    return fmaxf(o, 0.f);
}

// One block per (b,c) slice: simulate the 4-stage border program in LDS.
__global__ __launch_bounds__(256) void border_kernel(
    const float* __restrict__ x,
    const float* __restrict__ w1, const float* __restrict__ b1,
    const float* __restrict__ w2, const float* __restrict__ b2,
    const float* __restrict__ w3, const float* __restrict__ b3,
    float* __restrict__ out)
{
    const int tid = threadIdx.x;
    const int bc  = blockIdx.x;                     // b*128 + c, 0..1023
    const float* xs = x + (size_t)bc * 65536;       // 256*256 slice
    float*       os = out + (size_t)bc * 67600;     // 260*260 slice

    // Tracked xp rows/cols {0,1,2,3,255,256,257,258,259}; colS[ci][r] = xp[r][col]
    __shared__ float rowS[9][260];
    __shared__ float colS[9][260];
    __shared__ float W1[4][8][6];
    __shared__ float B1[4][8];
    __shared__ float W2[4][8][8];
    __shared__ float B2[4][8];
    __shared__ float W3[4][8];
    __shared__ float B3[4];

    // zero-init tracked lines (frame cells start at 0, corners stay 0)
    for (int idx = tid; idx < 9 * 260; idx += 256) {
        (&rowS[0][0])[idx] = 0.f;
        (&colS[0][0])[idx] = 0.f;
    }
    // stage weights into LDS (layouts match global flattening exactly)
    for (int idx = tid; idx < 4 * 8 * 6; idx += 256) (&W1[0][0][0])[idx] = w1[idx];
    for (int idx = tid; idx < 4 * 8 * 8; idx += 256) (&W2[0][0][0])[idx] = w2[idx];
    if (tid < 32) {
        (&B1[0][0])[tid] = b1[tid];
        (&B2[0][0])[tid] = b2[tid];
        (&W3[0][0])[tid] = w3[tid];
    }
    if (tid < 4) B3[tid] = b3[tid];
    __syncthreads();

    // Load x into tracked lines:
    // xp rows 2,3 = x rows 0,1 ; xp rows 255,256,257 = x rows 253,254,255
    for (int which = 0; which < 5; ++which) {
        int xr = which < 2 ? which : 251 + which;   // 0,1,253,254,255
        rowS[2 + which][2 + tid] = xs[xr * 256 + tid];
        colS[2 + which][2 + tid] = xs[tid * 256 + xr];
    }
    __syncthreads();

    for (int it = 0; it < 2; ++it) {
        // ---- horizontal stage: top (s=0) and bottom (s=1) ----
        for (int task = tid; task < 516; task += 256) {
            int s, j;
            int rin0, rin1, rout;
            if (task < 258) { s = 0; j = task + 1;       rin0 = 2 - it;   rin1 = 3 - it;   rout = 1 - it; }
            else            { s = 1; j = task - 258 + 1; rin0 = 255 + it; rin1 = 256 + it; rout = 258 + it; }
            int a0 = bmap(rin0), a1 = bmap(rin1);
            float v[6];
            v[0] = rowS[a0][j - 1]; v[1] = rowS[a0][j]; v[2] = rowS[a0][j + 1];
            v[3] = rowS[a1][j - 1]; v[4] = rowS[a1][j]; v[5] = rowS[a1][j + 1];
            float o = mlp6(v, &W1[s][0][0], B1[s], &W2[s][0][0], B2[s], W3[s], B3[s]);
            rowS[bmap(rout)][j] = o;
            if (j < 4 || j >= 255) colS[bmap(j)][rout] = o;   // keep col views consistent
        }
        __syncthreads();
        // ---- vertical stage: left (s=2) and right (s=3) ----
        for (int task = tid; task < 516; task += 256) {
            int s, r;
            int cin0, cin1, cout;
            if (task < 258) { s = 2; r = task + 1;       cin0 = 2 - it;   cin1 = 3 - it;   cout = 1 - it; }
            else            { s = 3; r = task - 258 + 1; cin0 = 255 + it; cin1 = 256 + it; cout = 258 + it; }
            int a0 = bmap(cin0), a1 = bmap(cin1);
            float v[6];
            v[0] = colS[a0][r - 1]; v[1] = colS[a0][r]; v[2] = colS[a0][r + 1];
            v[3] = colS[a1][r - 1]; v[4] = colS[a1][r]; v[5] = colS[a1][r + 1];
            float o = mlp6(v, &W1[s][0][0], B1[s], &W2[s][0][0], B2[s], W3[s], B3[s]);
            colS[bmap(cout)][r] = o;
            if (r < 4 || r >= 255) rowS[bmap(r)][cout] = o;   // keep row views consistent
        }
        __syncthreads();
    }

    // ---- write final frame ----
    // rows 0,1,258,259 (full 260 wide)
    for (int idx = tid; idx < 4 * 260; idx += 256) {
        int w = idx / 260, cc = idx % 260;
        int rr = w < 2 ? w : 256 + w;               // 0,1,258,259
        os[(size_t)rr * 260 + cc] = rowS[bmap(rr)][cc];
    }
    // cols 0,1,258,259 for rows 2..257
    for (int idx = tid; idx < 4 * 256; idx += 256) {
        int w = idx >> 8, r = (idx & 255) + 2;
        int cc = w < 2 ? w : 256 + w;               // 0,1,258,259
        os[(size_t)r * 260 + cc] = colS[bmap(cc)][r];
    }
}

// Interior copy: x (b,c,r,0..255) -> xp (b,c,r+2, 2..257). Dest rows start at
// byte offset ≡ 8 (mod 16) -> float2 is the widest aligned vector.
__global__ __launch_bounds__(256) void copy_kernel(const float* __restrict__ x,
                                                   float* __restrict__ out)
{
    const int n2 = 8 * 128 * 256 * 128;             // total float2 = 33554432
    int i = blockIdx.x * 256 + threadIdx.x;
    const int stride = gridDim.x * 256;
    for (; i < n2; i += stride) {
        int row = i >> 7;                           // bc*256 + r
        int pos = (i & 127) << 1;                   // float offset within row
        int bc  = row >> 8;
        int r   = row & 255;
        const float2 val = *(const float2*)(x + ((size_t)row << 8) + pos);
        *(float2*)(out + (size_t)bc * 67600 + (r + 2) * 260 + 2 + pos) = val;
    }
}

extern "C" void kernel_launch(void* const* d_in, const int* in_sizes, int n_in,
                              void* d_out, int out_size, void* d_ws, size_t ws_size,
                              hipStream_t stream)
{
    const float* x  = (const float*)d_in[0];
    const float* w1 = (const float*)d_in[1];
    const float* b1 = (const float*)d_in[2];
    const float* w2 = (const float*)d_in[3];
    const float* b2 = (const float*)d_in[4];
    const float* w3 = (const float*)d_in[5];
    const float* b3 = (const float*)d_in[6];
    float* out = (float*)d_out;

    copy_kernel<<<2048, 256, 0, stream>>>(x, out);
    border_kernel<<<1024, 256, 0, stream>>>(x, w1, b1, w2, b2, w3, b3, out);
}